// Round 9
// baseline (11315.091 us; speedup 1.0000x reference)
//
#include <hip/hip_runtime.h>
#include <stdint.h>

#define T_LEN 512
#define H_DIM 512
#define B_TOT 4096
#define GATE_D 514
#define CLUSTERS 16
#define RANKS 16        // blocks per cluster
#define CROWS 256       // batch rows per cluster
#define OWNC 32         // h-columns owned per block
#define NTHR 512        // 8 waves
#define BARPAD 64       // uints between cluster counters (256B)

typedef short s16x8 __attribute__((ext_vector_type(8)));
typedef float f32x4 __attribute__((ext_vector_type(4)));

__device__ __forceinline__ ushort f2bf(float f) {
    uint32_t u = __builtin_bit_cast(uint32_t, f);
    u += 0x7FFF + ((u >> 16) & 1);     // RNE
    return (ushort)(u >> 16);
}
__device__ __forceinline__ float sigmoid_f(float x) {
    return 1.0f / (1.0f + __expf(-x));
}
__device__ __forceinline__ float tanh_f(float x) {
    float ax = fabsf(x);
    float e  = __expf(2.0f * ax);
    float t  = 1.0f - 2.0f / (e + 1.0f);
    return copysignf(t, x);
}
__device__ __forceinline__ void vm0() {
    asm volatile("s_waitcnt vmcnt(0)" ::: "memory");
}

// ---------------- K0: masked mean over time ----------------
__global__ void k_xmean(const float* __restrict__ x, const float* __restrict__ m,
                        float* __restrict__ xmean) {
    int b = blockIdx.x;
    int l = threadIdx.x;
    const float* xr = x + (size_t)b * T_LEN;
    const float* mr = m + (size_t)b * T_LEN;
    float sx = 0.f, sm = 0.f;
    #pragma unroll
    for (int i = 0; i < T_LEN / 64; ++i) {
        float mv = mr[l + i * 64];
        sx += xr[l + i * 64] * mv;
        sm += mv;
    }
    for (int off = 32; off; off >>= 1) {
        sx += __shfl_down(sx, off);
        sm += __shfl_down(sm, off);
    }
    if (l == 0) xmean[b] = sx / sm;
}

// ---------------- K_init: zero padded cluster barrier slots ----------------
__global__ void k_init(unsigned int* barc) {
    int i = threadIdx.x + blockIdx.x * blockDim.x;
    if (i < CLUSTERS * BARPAD) barc[i] = 0u;
}

// ---------------- fenced (cross-XCD-safe) cluster barrier — round-4/8 proven ----------------
__device__ __forceinline__ void bar_slow(unsigned int* cnt, unsigned int target) {
    vm0();
    __syncthreads();
    if (threadIdx.x == 0) {
        __builtin_amdgcn_fence(__ATOMIC_RELEASE, "agent");
        __hip_atomic_fetch_add(cnt, 1u, __ATOMIC_RELAXED, __HIP_MEMORY_SCOPE_AGENT);
        while (__hip_atomic_load(cnt, __ATOMIC_RELAXED, __HIP_MEMORY_SCOPE_AGENT) < target)
            __builtin_amdgcn_s_sleep(1);
        __builtin_amdgcn_fence(__ATOMIC_ACQUIRE, "agent");
    }
    __syncthreads();
}

// ---------------- same-XCD cluster barrier (round-8 proven) ----------------
// L1 is write-through: after vmcnt drain, plain stores are in the shared L2.
// Release needs no wbl2; acquire = per-CU L1 flash-invalidate only.
__device__ __forceinline__ void bar_fast(unsigned int* cnt, unsigned int target) {
    vm0();
    __syncthreads();
    if (threadIdx.x == 0) {
        __hip_atomic_fetch_add(cnt, 1u, __ATOMIC_RELAXED, __HIP_MEMORY_SCOPE_AGENT);
        while (__hip_atomic_load(cnt, __ATOMIC_RELAXED, __HIP_MEMORY_SCOPE_AGENT) < target)
            __builtin_amdgcn_s_sleep(1);
        asm volatile("buffer_inv" ::: "memory");
        vm0();
    }
    __syncthreads();
}

// ---------------- main persistent kernel ----------------
// 256 blocks x 512 threads. Cluster = 16 blocks sharing 256 batch rows (same-XCD by
// b%8 heuristic, runtime-verified via HW_REG_XCC_ID; non-uniform clusters fall back
// to the fenced barrier). Block rank j owns 32 output cols: weights in LDS/regs,
// fp32 h-state in 16 REGISTERS/thread. Per step: GEMM1(z,r) -> exchange r*hd ->
// GEMM2(h~) with fused gamma(t+1) decay; exchange via L2-hot global buffers.
__global__ __launch_bounds__(NTHR, 2) void k_grud(
    const float* __restrict__ x,   const float* __restrict__ xl,
    const float* __restrict__ itv, const float* __restrict__ msk,
    const float* __restrict__ Wgx, const float* __restrict__ bgx,
    const float* __restrict__ Wgh, const float* __restrict__ bgh,
    const float* __restrict__ Wz,  const float* __restrict__ bz,
    const float* __restrict__ Wr,  const float* __restrict__ br,
    const float* __restrict__ Wh,  const float* __restrict__ bh,
    const float* __restrict__ Wo,  const float* __restrict__ bo,
    const float* __restrict__ xmean,
    ushort* __restrict__ hdx, ushort* __restrict__ rhx,
    float* __restrict__ osum, unsigned int* __restrict__ barc,
    float* __restrict__ out)
{
    __shared__ ushort wfrag[80 * 512];        // 81920 B  B-frags: z 0-31, r 32-63, h(kt8-15) 64-79
    __shared__ ushort stage[16 * 512];        // 16384 B  linear frag image (rhd / hd-next)
    __shared__ float  xi_s[2][CROWS], mts_s[2][CROWS], its_s[2][CROWS];  // 6144 B
    __shared__ float4 epi_s[96];              // 1536 B   {bias, W[:,0], W[:,513]} per gate/own col
    __shared__ float2 ghb_s[OWNC];            // 256 B    {Wgh, bgh} own cols
    __shared__ unsigned int flag_s;

    const int tid = threadIdx.x;
    const int b   = blockIdx.x;
    const int cluster = (b & 7) * 2 + ((b >> 3) >> 4);   // same-XCD grouping heuristic
    const int rank    = (b >> 3) & 15;
    const int wv = tid >> 6, l = tid & 63;
    const int colb = l & 15, qg = l >> 4;
    const int r0 = cluster * CROWS;

    unsigned int* cnt     = barc + cluster * BARPAD;   // line 0 of the 256B slot
    unsigned int* xcd_arr = cnt + 16;                  // line 1: per-rank XCC ids
    ushort* hdc = hdx + (size_t)cluster * CROWS * H_DIM;
    ushort* rhc = rhx + (size_t)cluster * CROWS * H_DIM;
    const s16x8* WF = (const s16x8*)wfrag;
    const s16x8* HD = (const s16x8*)hdc;
    const s16x8* RH = (const s16x8*)rhc;

    // ---- one-time init: weight fragments (LDS) ----
    for (int s = tid; s < 80 * 64; s += NTHR) {
        int fi = s >> 6, ln = s & 63;
        const float* W; int kt, ntl;
        if (fi < 64) { int g = fi >> 5; W = g ? Wr : Wz; int id = fi & 31; ntl = id >> 4; kt = id & 15; }
        else         { int id = fi - 64; W = Wh; ntl = id >> 3; kt = 8 + (id & 7); }
        int colg = rank * OWNC + ntl * 16 + (ln & 15);
        int c0 = 1 + kt * 32 + (ln >> 4) * 8;
        ushort tb[8];
        #pragma unroll
        for (int j = 0; j < 8; ++j) tb[j] = f2bf(W[(size_t)colg * GATE_D + c0 + j]);
        *(s16x8*)&wfrag[s * 8] = *(s16x8*)tb;
    }
    // ---- Wh kt 0..7 B-frags in registers (identical across waves) ----
    s16x8 whreg[16];
    #pragma unroll
    for (int nt = 0; nt < 2; ++nt)
        #pragma unroll
        for (int kt = 0; kt < 8; ++kt) {
            int colg = rank * OWNC + nt * 16 + (l & 15);
            int c0 = 1 + kt * 32 + (l >> 4) * 8;
            ushort tb[8];
            #pragma unroll
            for (int j = 0; j < 8; ++j) tb[j] = f2bf(Wh[(size_t)colg * GATE_D + c0 + j]);
            whreg[nt * 8 + kt] = *(s16x8*)tb;
        }
    for (int i = tid; i < 96; i += NTHR) {
        int g = i >> 5, c = i & 31;
        const float* W  = (g == 0) ? Wz : (g == 1) ? Wr : Wh;
        const float* bb = (g == 0) ? bz : (g == 1) ? br : bh;
        int colg = rank * OWNC + c;
        epi_s[i] = make_float4(bb[colg], W[(size_t)colg * GATE_D],
                               W[(size_t)colg * GATE_D + GATE_D - 1], 0.f);
    }
    if (tid < OWNC) ghb_s[tid] = make_float2(Wgh[rank * OWNC + tid], bgh[rank * OWNC + tid]);
    const float wgx = Wgx[0], bgx0 = bgx[0];

    // ---- zero our hdc fragment slice (hd(0) = 0) ----
    #pragma unroll
    for (int i = 0; i < 2; ++i) {
        int s = tid + i * NTHR;
        *(s16x8*)((char*)hdc + ((size_t)(s >> 6) * 1024 + (size_t)rank * 64 + (s & 63)) * 16) = (s16x8){0,0,0,0,0,0,0,0};
    }

    // ---- per-row scalars for t=0 -> slot 0; cache xmean ----
    float xmv = 0.f;
    if (tid < CROWS) {
        xmv = xmean[r0 + tid];
        size_t idx = (size_t)(r0 + tid) * T_LEN;
        float xv = x[idx], xlv = xl[idx], iv = itv[idx], mv = msk[idx];
        float gx = __expf(-fmaxf(iv * wgx + bgx0, 0.f));
        xi_s[0][tid]  = mv * xv + (1.f - mv) * (gx * xlv + (1.f - gx) * xmv);
        mts_s[0][tid] = mv;
        its_s[0][tid] = iv;
    }

    // ---- registration: publish XCC_ID, fenced barrier, verify cluster uniformity ----
    if (tid == 0) {
        unsigned int myxcc;
        asm volatile("s_getreg_b32 %0, hwreg(HW_REG_XCC_ID)" : "=s"(myxcc));
        xcd_arr[rank] = myxcc;
    }
    unsigned int ep = 1;
    bar_slow(cnt, RANKS * ep);                 // epoch 1 (also flushes hdc zeros)
    if (tid == 0) {
        unsigned int x0 = xcd_arr[0], same = 1;
        #pragma unroll
        for (int rk = 1; rk < RANKS; ++rk) same &= (xcd_arr[rk] == x0) ? 1u : 0u;
        flag_s = same;
    }
    __syncthreads();
    const bool fastc = (flag_s != 0);

    float hdq[2][2][4];                        // fp32 h-state in registers (decayed hd)
    #pragma unroll
    for (int mt = 0; mt < 2; ++mt)
        #pragma unroll
        for (int nt = 0; nt < 2; ++nt)
            #pragma unroll
            for (int q = 0; q < 4; ++q) hdq[mt][nt][q] = 0.f;
    float zq[2][2][4];

    for (int t = 0; t < T_LEN; ++t) {
        const int sl = t & 1;

        // ---- GEMM1: z,r = hd (256x512) x W (512x64), wave rows [32wv, 32wv+32) ----
        f32x4 accz[2][2], accr[2][2];
        #pragma unroll
        for (int mt = 0; mt < 2; ++mt)
            #pragma unroll
            for (int nt = 0; nt < 2; ++nt) { accz[mt][nt] = (f32x4){0,0,0,0}; accr[mt][nt] = (f32x4){0,0,0,0}; }
        #pragma unroll
        for (int kt = 0; kt < 16; ++kt) {
            s16x8 a0 = HD[((2 * wv    ) * 16 + kt) * 64 + l];
            s16x8 a1 = HD[((2 * wv + 1) * 16 + kt) * 64 + l];
            #pragma unroll
            for (int nt = 0; nt < 2; ++nt) {
                s16x8 bz_ = WF[(     nt * 16 + kt) * 64 + l];
                s16x8 br_ = WF[(32 + nt * 16 + kt) * 64 + l];
                accz[0][nt] = __builtin_amdgcn_mfma_f32_16x16x32_bf16(a0, bz_, accz[0][nt], 0, 0, 0);
                accz[1][nt] = __builtin_amdgcn_mfma_f32_16x16x32_bf16(a1, bz_, accz[1][nt], 0, 0, 0);
                accr[0][nt] = __builtin_amdgcn_mfma_f32_16x16x32_bf16(a0, br_, accr[0][nt], 0, 0, 0);
                accr[1][nt] = __builtin_amdgcn_mfma_f32_16x16x32_bf16(a1, br_, accr[1][nt], 0, 0, 0);
            }
        }
        // ---- z,r epilogue: z -> regs, r*hd -> stage (linear frag image) ----
        #pragma unroll
        for (int mt = 0; mt < 2; ++mt) {
            #pragma unroll
            for (int nt = 0; nt < 2; ++nt) {
                int c = nt * 16 + colb;
                float4 ez = epi_s[c];
                float4 er = epi_s[32 + c];
                int grp = (c >> 3) & 3, jj = c & 7;
                #pragma unroll
                for (int q = 0; q < 4; ++q) {
                    int row = wv * 32 + mt * 16 + qg * 4 + q;
                    float xiv = xi_s[sl][row], mtv = mts_s[sl][row];
                    zq[mt][nt][q] = sigmoid_f(accz[mt][nt][q] + ez.x + xiv * ez.y + mtv * ez.z);
                    float rr = sigmoid_f(accr[mt][nt][q] + er.x + xiv * er.y + mtv * er.z);
                    stage[(((2 * wv + mt) * 64) + (qg * 4 + q) + grp * 16) * 8 + jj] =
                        f2bf(rr * hdq[mt][nt][q]);
                }
            }
        }
        __syncthreads();
        // ---- copy stage -> rhc (contiguous b128 reads, 16B global stores) ----
        #pragma unroll
        for (int i = 0; i < 2; ++i) {
            int s = tid + i * NTHR;
            *(s16x8*)((char*)rhc + ((size_t)(s >> 6) * 1024 + (size_t)rank * 64 + (s & 63)) * 16) =
                *(const s16x8*)&stage[s * 8];
        }
        // ---- barrier 2, split: arrive / prefetch t+1 scalars / wait ----
        ++ep;
        {
            unsigned int target = RANKS * ep;
            vm0();
            __syncthreads();
            if (tid == 0) {
                if (!fastc) __builtin_amdgcn_fence(__ATOMIC_RELEASE, "agent");
                __hip_atomic_fetch_add(cnt, 1u, __ATOMIC_RELAXED, __HIP_MEMORY_SCOPE_AGENT);
            }
            if (tid < CROWS && t + 1 < T_LEN) {    // overlap: scalars for t+1
                size_t idx = (size_t)(r0 + tid) * T_LEN + t + 1;
                float xv = x[idx], xlv = xl[idx], iv = itv[idx], mv = msk[idx];
                float gx = __expf(-fmaxf(iv * wgx + bgx0, 0.f));
                int s2 = sl ^ 1;
                xi_s[s2][tid]  = mv * xv + (1.f - mv) * (gx * xlv + (1.f - gx) * xmv);
                mts_s[s2][tid] = mv;
                its_s[s2][tid] = iv;
            }
            if (tid == 0) {
                while (__hip_atomic_load(cnt, __ATOMIC_RELAXED, __HIP_MEMORY_SCOPE_AGENT) < target)
                    __builtin_amdgcn_s_sleep(1);
                if (fastc) { asm volatile("buffer_inv" ::: "memory"); vm0(); }
                else __builtin_amdgcn_fence(__ATOMIC_ACQUIRE, "agent");
            }
            __syncthreads();
        }

        // ---- GEMM2: h~ = (r*hd) x Wh (512x32); Wh kt<8 from registers ----
        f32x4 acc2[2][2];
        #pragma unroll
        for (int mt = 0; mt < 2; ++mt)
            #pragma unroll
            for (int nt = 0; nt < 2; ++nt) acc2[mt][nt] = (f32x4){0,0,0,0};
        #pragma unroll
        for (int kt = 0; kt < 16; ++kt) {
            s16x8 a0 = RH[((2 * wv    ) * 16 + kt) * 64 + l];
            s16x8 a1 = RH[((2 * wv + 1) * 16 + kt) * 64 + l];
            #pragma unroll
            for (int nt = 0; nt < 2; ++nt) {
                s16x8 bh_ = (kt < 8) ? whreg[nt * 8 + kt]
                                     : WF[(64 + nt * 8 + (kt - 8)) * 64 + l];
                acc2[0][nt] = __builtin_amdgcn_mfma_f32_16x16x32_bf16(a0, bh_, acc2[0][nt], 0, 0, 0);
                acc2[1][nt] = __builtin_amdgcn_mfma_f32_16x16x32_bf16(a1, bh_, acc2[1][nt], 0, 0, 0);
            }
        }
        // ---- h~ epilogue + fused state update + fused gamma(t+1) decay ----
        const bool last = (t + 1 == T_LEN);
        #pragma unroll
        for (int mt = 0; mt < 2; ++mt) {
            #pragma unroll
            for (int nt = 0; nt < 2; ++nt) {
                int c = nt * 16 + colb;
                float4 eh = epi_s[64 + c];
                float2 gb = ghb_s[c];
                int grp = (c >> 3) & 3, jj = c & 7;
                #pragma unroll
                for (int q = 0; q < 4; ++q) {
                    int row = wv * 32 + mt * 16 + qg * 4 + q;
                    float ht = tanh_f(acc2[mt][nt][q] + eh.x + xi_s[sl][row] * eh.y + mts_s[sl][row] * eh.z);
                    float hd = hdq[mt][nt][q];
                    float hn = hd + zq[mt][nt][q] * (ht - hd);
                    float g  = last ? 1.f : __expf(-fmaxf(its_s[sl ^ 1][row] * gb.x + gb.y, 0.f));
                    float hdn = hn * g;
                    hdq[mt][nt][q] = hdn;
                    if (!last)
                        stage[(((2 * wv + mt) * 64) + (qg * 4 + q) + grp * 16) * 8 + jj] = f2bf(hdn);
                }
            }
        }
        __syncthreads();
        if (!last) {
            // ---- copy stage -> hdc ----
            #pragma unroll
            for (int i = 0; i < 2; ++i) {
                int s = tid + i * NTHR;
                *(s16x8*)((char*)hdc + ((size_t)(s >> 6) * 1024 + (size_t)rank * 64 + (s & 63)) * 16) =
                    *(const s16x8*)&stage[s * 8];
            }
        }
        ++ep;
        if (fastc) bar_fast(cnt, RANKS * ep); else bar_slow(cnt, RANKS * ep);
    }

    // ---- output head: per-thread partials over own cols, 16-lane shfl reduce ----
    {
        float wo0 = Wo[rank * OWNC + colb];
        float wo1 = Wo[rank * OWNC + 16 + colb];
        #pragma unroll
        for (int mt = 0; mt < 2; ++mt) {
            #pragma unroll
            for (int q = 0; q < 4; ++q) {
                int row = wv * 32 + mt * 16 + qg * 4 + q;
                float p = hdq[mt][0][q] * wo0 + hdq[mt][1][q] * wo1;
                #pragma unroll
                for (int off = 1; off < 16; off <<= 1) p += __shfl_xor(p, off);
                if (colb == 0) osum[(size_t)(r0 + row) * RANKS + rank] = p;
            }
        }
    }
    ++ep;
    if (fastc) bar_fast(cnt, RANKS * ep); else bar_slow(cnt, RANKS * ep);
    if (rank == 0 && tid < CROWS) {
        float s = 0.f;
        #pragma unroll
        for (int rk = 0; rk < RANKS; ++rk) s += osum[(size_t)(r0 + tid) * RANKS + rk];
        out[r0 + tid] = sigmoid_f(s + bo[0]);
    }
}

extern "C" void kernel_launch(void* const* d_in, const int* in_sizes, int n_in,
                              void* d_out, int out_size, void* d_ws, size_t ws_size,
                              hipStream_t stream) {
    const float* x    = (const float*)d_in[0];
    const float* xl   = (const float*)d_in[1];
    const float* itv  = (const float*)d_in[2];
    const float* msk  = (const float*)d_in[3];
    const float* Wgx  = (const float*)d_in[4];
    const float* bgx  = (const float*)d_in[5];
    const float* Wgh  = (const float*)d_in[6];
    const float* bgh  = (const float*)d_in[7];
    const float* Wz   = (const float*)d_in[8];
    const float* bz   = (const float*)d_in[9];
    const float* Wr   = (const float*)d_in[10];
    const float* br   = (const float*)d_in[11];
    const float* Wh   = (const float*)d_in[12];
    const float* bh   = (const float*)d_in[13];
    const float* Wo   = (const float*)d_in[14];
    const float* bo   = (const float*)d_in[15];

    char* ws = (char*)d_ws;
    float*        xmean = (float*)ws;                          // 16384 B
    unsigned int* barc  = (unsigned int*)(ws + 16384);         // 16*256 B (counter + xcd slots)
    float*        osum  = (float*)(ws + 16384 + 4096);         // 262144 B
    ushort*       hdx   = (ushort*)(ws + 16384 + 4096 + 262144);            // 4 MB
    ushort*       rhx   = (ushort*)(ws + 16384 + 4096 + 262144 + 4194304);  // 4 MB

    k_init<<<1, 1024, 0, stream>>>(barc);
    k_xmean<<<B_TOT, 64, 0, stream>>>(x, msk, xmean);
    k_grud<<<CLUSTERS * RANKS, NTHR, 0, stream>>>(
        x, xl, itv, msk, Wgx, bgx, Wgh, bgh,
        Wz, bz, Wr, br, Wh, bh, Wo, bo,
        xmean, hdx, rhx, osum, barc, (float*)d_out);
}

// Round 10
// 6998.195 us; speedup vs baseline: 1.6169x; 1.6169x over previous
//
#include <hip/hip_runtime.h>
#include <stdint.h>

#define T_LEN 512
#define H_DIM 512
#define B_TOT 4096
#define GATE_D 514
#define CLUSTERS 16
#define RANKS 16        // blocks per cluster
#define CROWS 256       // batch rows per cluster
#define OWNC 32         // h-columns owned per block
#define NTHR 512        // 8 waves
#define BARPAD 64       // uints between cluster counters (256B)

typedef short s16x8 __attribute__((ext_vector_type(8)));
typedef float f32x4 __attribute__((ext_vector_type(4)));

__device__ __forceinline__ ushort f2bf(float f) {
    uint32_t u = __builtin_bit_cast(uint32_t, f);
    u += 0x7FFF + ((u >> 16) & 1);     // RNE
    return (ushort)(u >> 16);
}
__device__ __forceinline__ float sigmoid_f(float x) {
    return 1.0f / (1.0f + __expf(-x));
}
__device__ __forceinline__ float tanh_f(float x) {
    float ax = fabsf(x);
    float e  = __expf(2.0f * ax);
    float t  = 1.0f - 2.0f / (e + 1.0f);
    return copysignf(t, x);
}
__device__ __forceinline__ void vm0() {
    asm volatile("s_waitcnt vmcnt(0)" ::: "memory");
}

// ---------------- K0: masked mean over time ----------------
__global__ void k_xmean(const float* __restrict__ x, const float* __restrict__ m,
                        float* __restrict__ xmean) {
    int b = blockIdx.x;
    int l = threadIdx.x;
    const float* xr = x + (size_t)b * T_LEN;
    const float* mr = m + (size_t)b * T_LEN;
    float sx = 0.f, sm = 0.f;
    #pragma unroll
    for (int i = 0; i < T_LEN / 64; ++i) {
        float mv = mr[l + i * 64];
        sx += xr[l + i * 64] * mv;
        sm += mv;
    }
    for (int off = 32; off; off >>= 1) {
        sx += __shfl_down(sx, off);
        sm += __shfl_down(sm, off);
    }
    if (l == 0) xmean[b] = sx / sm;
}

// ---------------- K_init: zero padded cluster barrier slots ----------------
__global__ void k_init(unsigned int* barc) {
    int i = threadIdx.x + blockIdx.x * blockDim.x;
    if (i < CLUSTERS * BARPAD) barc[i] = 0u;
}

// ---------------- fenced (cross-XCD-safe) cluster barrier — round-4/8 proven ----------------
__device__ __forceinline__ void bar_slow(unsigned int* cnt, unsigned int target) {
    vm0();
    __syncthreads();
    if (threadIdx.x == 0) {
        __builtin_amdgcn_fence(__ATOMIC_RELEASE, "agent");
        __hip_atomic_fetch_add(cnt, 1u, __ATOMIC_RELAXED, __HIP_MEMORY_SCOPE_AGENT);
        while (__hip_atomic_load(cnt, __ATOMIC_RELAXED, __HIP_MEMORY_SCOPE_AGENT) < target)
            __builtin_amdgcn_s_sleep(1);
        __builtin_amdgcn_fence(__ATOMIC_ACQUIRE, "agent");
    }
    __syncthreads();
}

// ---------------- same-XCD cluster barrier (round-8 proven) ----------------
// L1 is write-through: after vmcnt drain, plain stores are in the shared L2.
// Release needs no wbl2; acquire = per-CU L1 flash-invalidate only.
__device__ __forceinline__ void bar_fast(unsigned int* cnt, unsigned int target) {
    vm0();
    __syncthreads();
    if (threadIdx.x == 0) {
        __hip_atomic_fetch_add(cnt, 1u, __ATOMIC_RELAXED, __HIP_MEMORY_SCOPE_AGENT);
        while (__hip_atomic_load(cnt, __ATOMIC_RELAXED, __HIP_MEMORY_SCOPE_AGENT) < target)
            __builtin_amdgcn_s_sleep(1);
        asm volatile("buffer_inv" ::: "memory");
        vm0();
    }
    __syncthreads();
}

// ---------------- main persistent kernel ----------------
// 256 blocks x 512 threads, 1 block/CU (LDS-limited). Cluster = 16 blocks sharing
// 256 batch rows (same-XCD by b%8 heuristic, runtime-verified; fenced fallback).
// Block rank j owns 32 output cols: all weight B-frags in LDS, fp32 h-state in 16
// registers/thread. Per step: GEMM1(z,r) -> exchange r*hd -> GEMM2(h~) with fused
// gamma(t+1); exchange via L2-hot global buffers. NOTE: no min-occupancy arg in
// launch_bounds — LDS already caps at 1 block/CU, so the 256-VGPR budget is free
// (round 9's (512,2) pinned VGPR=128 and spilled whreg/hdq to scratch: 11 GB HBM).
__global__ __launch_bounds__(NTHR) void k_grud(
    const float* __restrict__ x,   const float* __restrict__ xl,
    const float* __restrict__ itv, const float* __restrict__ msk,
    const float* __restrict__ Wgx, const float* __restrict__ bgx,
    const float* __restrict__ Wgh, const float* __restrict__ bgh,
    const float* __restrict__ Wz,  const float* __restrict__ bz,
    const float* __restrict__ Wr,  const float* __restrict__ br,
    const float* __restrict__ Wh,  const float* __restrict__ bh,
    const float* __restrict__ Wo,  const float* __restrict__ bo,
    const float* __restrict__ xmean,
    ushort* __restrict__ hdx, ushort* __restrict__ rhx,
    float* __restrict__ osum, unsigned int* __restrict__ barc,
    float* __restrict__ out)
{
    __shared__ ushort wfrag[96 * 512];        // 98304 B  B-frags: z 0-31, r 32-63, h 64-95
    __shared__ ushort stage[16 * 512];        // 16384 B  linear frag image (rhd / hd-next)
    __shared__ float  xi_s[2][CROWS], mts_s[2][CROWS], its_s[2][CROWS];  // 6144 B
    __shared__ float4 epi_s[96];              // 1536 B   {bias, W[:,0], W[:,513]} per gate/own col
    __shared__ float2 ghb_s[OWNC];            // 256 B    {Wgh, bgh} own cols
    __shared__ unsigned int flag_s;

    const int tid = threadIdx.x;
    const int b   = blockIdx.x;
    const int cluster = (b & 7) * 2 + ((b >> 3) >> 4);   // same-XCD grouping heuristic
    const int rank    = (b >> 3) & 15;
    const int wv = tid >> 6, l = tid & 63;
    const int colb = l & 15, qg = l >> 4;
    const int r0 = cluster * CROWS;

    unsigned int* cnt     = barc + cluster * BARPAD;   // line 0 of the 256B slot
    unsigned int* xcd_arr = cnt + 16;                  // line 1: per-rank XCC ids
    ushort* hdc = hdx + (size_t)cluster * CROWS * H_DIM;
    ushort* rhc = rhx + (size_t)cluster * CROWS * H_DIM;
    const s16x8* WF = (const s16x8*)wfrag;
    const s16x8* HD = (const s16x8*)hdc;
    const s16x8* RH = (const s16x8*)rhc;

    // ---- one-time init: weight fragments (LDS), round-8 layout ----
    for (int s = tid; s < 96 * 64; s += NTHR) {
        int fi = s >> 6, ln = s & 63;
        int g = fi >> 5, nt = (fi >> 4) & 1, kt = fi & 15;
        const float* W = (g == 0) ? Wz : (g == 1) ? Wr : Wh;
        int colg = rank * OWNC + nt * 16 + (ln & 15);
        int c0 = 1 + kt * 32 + (ln >> 4) * 8;
        ushort tb[8];
        #pragma unroll
        for (int j = 0; j < 8; ++j) tb[j] = f2bf(W[(size_t)colg * GATE_D + c0 + j]);
        *(s16x8*)&wfrag[s * 8] = *(s16x8*)tb;
    }
    for (int i = tid; i < 96; i += NTHR) {
        int g = i >> 5, c = i & 31;
        const float* W  = (g == 0) ? Wz : (g == 1) ? Wr : Wh;
        const float* bb = (g == 0) ? bz : (g == 1) ? br : bh;
        int colg = rank * OWNC + c;
        epi_s[i] = make_float4(bb[colg], W[(size_t)colg * GATE_D],
                               W[(size_t)colg * GATE_D + GATE_D - 1], 0.f);
    }
    if (tid < OWNC) ghb_s[tid] = make_float2(Wgh[rank * OWNC + tid], bgh[rank * OWNC + tid]);
    const float wgx = Wgx[0], bgx0 = bgx[0];

    // ---- zero our hdc fragment slice (hd(0) = 0) ----
    #pragma unroll
    for (int i = 0; i < 2; ++i) {
        int s = tid + i * NTHR;
        *(s16x8*)((char*)hdc + ((size_t)(s >> 6) * 1024 + (size_t)rank * 64 + (s & 63)) * 16) = (s16x8){0,0,0,0,0,0,0,0};
    }

    // ---- per-row scalars for t=0 -> slot 0; cache xmean ----
    float xmv = 0.f;
    if (tid < CROWS) {
        xmv = xmean[r0 + tid];
        size_t idx = (size_t)(r0 + tid) * T_LEN;
        float xv = x[idx], xlv = xl[idx], iv = itv[idx], mv = msk[idx];
        float gx = __expf(-fmaxf(iv * wgx + bgx0, 0.f));
        xi_s[0][tid]  = mv * xv + (1.f - mv) * (gx * xlv + (1.f - gx) * xmv);
        mts_s[0][tid] = mv;
        its_s[0][tid] = iv;
    }

    // ---- registration: publish XCC_ID, fenced barrier, verify cluster uniformity ----
    if (tid == 0) {
        unsigned int myxcc;
        asm volatile("s_getreg_b32 %0, hwreg(HW_REG_XCC_ID)" : "=s"(myxcc));
        xcd_arr[rank] = myxcc;
    }
    unsigned int ep = 1;
    bar_slow(cnt, RANKS * ep);                 // epoch 1 (also flushes hdc zeros)
    if (tid == 0) {
        unsigned int x0 = xcd_arr[0], same = 1;
        #pragma unroll
        for (int rk = 1; rk < RANKS; ++rk) same &= (xcd_arr[rk] == x0) ? 1u : 0u;
        flag_s = same;
    }
    __syncthreads();
    const bool fastc = (flag_s != 0);

    float hdq[2][2][4];                        // fp32 h-state in registers (decayed hd)
    #pragma unroll
    for (int mt = 0; mt < 2; ++mt)
        #pragma unroll
        for (int nt = 0; nt < 2; ++nt)
            #pragma unroll
            for (int q = 0; q < 4; ++q) hdq[mt][nt][q] = 0.f;
    float zq[2][2][4];

    for (int t = 0; t < T_LEN; ++t) {
        const int sl = t & 1;

        // ---- GEMM1: z,r = hd (256x512) x W (512x64), wave rows [32wv, 32wv+32) ----
        f32x4 accz[2][2], accr[2][2];
        #pragma unroll
        for (int mt = 0; mt < 2; ++mt)
            #pragma unroll
            for (int nt = 0; nt < 2; ++nt) { accz[mt][nt] = (f32x4){0,0,0,0}; accr[mt][nt] = (f32x4){0,0,0,0}; }
        #pragma unroll
        for (int kt = 0; kt < 16; ++kt) {
            s16x8 a0 = HD[((2 * wv    ) * 16 + kt) * 64 + l];
            s16x8 a1 = HD[((2 * wv + 1) * 16 + kt) * 64 + l];
            #pragma unroll
            for (int nt = 0; nt < 2; ++nt) {
                s16x8 bz_ = WF[(     nt * 16 + kt) * 64 + l];
                s16x8 br_ = WF[(32 + nt * 16 + kt) * 64 + l];
                accz[0][nt] = __builtin_amdgcn_mfma_f32_16x16x32_bf16(a0, bz_, accz[0][nt], 0, 0, 0);
                accz[1][nt] = __builtin_amdgcn_mfma_f32_16x16x32_bf16(a1, bz_, accz[1][nt], 0, 0, 0);
                accr[0][nt] = __builtin_amdgcn_mfma_f32_16x16x32_bf16(a0, br_, accr[0][nt], 0, 0, 0);
                accr[1][nt] = __builtin_amdgcn_mfma_f32_16x16x32_bf16(a1, br_, accr[1][nt], 0, 0, 0);
            }
        }
        // ---- z,r epilogue: z -> regs, r*hd -> stage (linear frag image) ----
        #pragma unroll
        for (int mt = 0; mt < 2; ++mt) {
            #pragma unroll
            for (int nt = 0; nt < 2; ++nt) {
                int c = nt * 16 + colb;
                float4 ez = epi_s[c];
                float4 er = epi_s[32 + c];
                int grp = (c >> 3) & 3, jj = c & 7;
                #pragma unroll
                for (int q = 0; q < 4; ++q) {
                    int row = wv * 32 + mt * 16 + qg * 4 + q;
                    float xiv = xi_s[sl][row], mtv = mts_s[sl][row];
                    zq[mt][nt][q] = sigmoid_f(accz[mt][nt][q] + ez.x + xiv * ez.y + mtv * ez.z);
                    float rr = sigmoid_f(accr[mt][nt][q] + er.x + xiv * er.y + mtv * er.z);
                    stage[(((2 * wv + mt) * 64) + (qg * 4 + q) + grp * 16) * 8 + jj] =
                        f2bf(rr * hdq[mt][nt][q]);
                }
            }
        }
        __syncthreads();
        // ---- copy stage -> rhc (contiguous b128 reads, 16B global stores) ----
        #pragma unroll
        for (int i = 0; i < 2; ++i) {
            int s = tid + i * NTHR;
            *(s16x8*)((char*)rhc + ((size_t)(s >> 6) * 1024 + (size_t)rank * 64 + (s & 63)) * 16) =
                *(const s16x8*)&stage[s * 8];
        }
        // ---- barrier 2, split: arrive / prefetch t+1 scalars / wait ----
        ++ep;
        {
            unsigned int target = RANKS * ep;
            vm0();
            __syncthreads();
            if (tid == 0) {
                if (!fastc) __builtin_amdgcn_fence(__ATOMIC_RELEASE, "agent");
                __hip_atomic_fetch_add(cnt, 1u, __ATOMIC_RELAXED, __HIP_MEMORY_SCOPE_AGENT);
            }
            if (tid < CROWS && t + 1 < T_LEN) {    // overlap: scalars for t+1
                size_t idx = (size_t)(r0 + tid) * T_LEN + t + 1;
                float xv = x[idx], xlv = xl[idx], iv = itv[idx], mv = msk[idx];
                float gx = __expf(-fmaxf(iv * wgx + bgx0, 0.f));
                int s2 = sl ^ 1;
                xi_s[s2][tid]  = mv * xv + (1.f - mv) * (gx * xlv + (1.f - gx) * xmv);
                mts_s[s2][tid] = mv;
                its_s[s2][tid] = iv;
            }
            if (tid == 0) {
                while (__hip_atomic_load(cnt, __ATOMIC_RELAXED, __HIP_MEMORY_SCOPE_AGENT) < target)
                    __builtin_amdgcn_s_sleep(1);
                if (fastc) { asm volatile("buffer_inv" ::: "memory"); vm0(); }
                else __builtin_amdgcn_fence(__ATOMIC_ACQUIRE, "agent");
            }
            __syncthreads();
        }

        // ---- GEMM2: h~ = (r*hd) x Wh (512x32) ----
        f32x4 acc2[2][2];
        #pragma unroll
        for (int mt = 0; mt < 2; ++mt)
            #pragma unroll
            for (int nt = 0; nt < 2; ++nt) acc2[mt][nt] = (f32x4){0,0,0,0};
        #pragma unroll
        for (int kt = 0; kt < 16; ++kt) {
            s16x8 a0 = RH[((2 * wv    ) * 16 + kt) * 64 + l];
            s16x8 a1 = RH[((2 * wv + 1) * 16 + kt) * 64 + l];
            #pragma unroll
            for (int nt = 0; nt < 2; ++nt) {
                s16x8 bh_ = WF[(64 + nt * 16 + kt) * 64 + l];
                acc2[0][nt] = __builtin_amdgcn_mfma_f32_16x16x32_bf16(a0, bh_, acc2[0][nt], 0, 0, 0);
                acc2[1][nt] = __builtin_amdgcn_mfma_f32_16x16x32_bf16(a1, bh_, acc2[1][nt], 0, 0, 0);
            }
        }
        // ---- h~ epilogue + fused state update + fused gamma(t+1) decay ----
        const bool last = (t + 1 == T_LEN);
        #pragma unroll
        for (int mt = 0; mt < 2; ++mt) {
            #pragma unroll
            for (int nt = 0; nt < 2; ++nt) {
                int c = nt * 16 + colb;
                float4 eh = epi_s[64 + c];
                float2 gb = ghb_s[c];
                int grp = (c >> 3) & 3, jj = c & 7;
                #pragma unroll
                for (int q = 0; q < 4; ++q) {
                    int row = wv * 32 + mt * 16 + qg * 4 + q;
                    float ht = tanh_f(acc2[mt][nt][q] + eh.x + xi_s[sl][row] * eh.y + mts_s[sl][row] * eh.z);
                    float hd = hdq[mt][nt][q];
                    float hn = hd + zq[mt][nt][q] * (ht - hd);
                    float g  = last ? 1.f : __expf(-fmaxf(its_s[sl ^ 1][row] * gb.x + gb.y, 0.f));
                    float hdn = hn * g;
                    hdq[mt][nt][q] = hdn;
                    if (!last)
                        stage[(((2 * wv + mt) * 64) + (qg * 4 + q) + grp * 16) * 8 + jj] = f2bf(hdn);
                }
            }
        }
        __syncthreads();
        if (!last) {
            // ---- copy stage -> hdc ----
            #pragma unroll
            for (int i = 0; i < 2; ++i) {
                int s = tid + i * NTHR;
                *(s16x8*)((char*)hdc + ((size_t)(s >> 6) * 1024 + (size_t)rank * 64 + (s & 63)) * 16) =
                    *(const s16x8*)&stage[s * 8];
            }
        }
        ++ep;
        if (fastc) bar_fast(cnt, RANKS * ep); else bar_slow(cnt, RANKS * ep);
    }

    // ---- output head: per-thread partials over own cols, 16-lane shfl reduce ----
    {
        float wo0 = Wo[rank * OWNC + colb];
        float wo1 = Wo[rank * OWNC + 16 + colb];
        #pragma unroll
        for (int mt = 0; mt < 2; ++mt) {
            #pragma unroll
            for (int q = 0; q < 4; ++q) {
                int row = wv * 32 + mt * 16 + qg * 4 + q;
                float p = hdq[mt][0][q] * wo0 + hdq[mt][1][q] * wo1;
                #pragma unroll
                for (int off = 1; off < 16; off <<= 1) p += __shfl_xor(p, off);
                if (colb == 0) osum[(size_t)(r0 + row) * RANKS + rank] = p;
            }
        }
    }
    ++ep;
    if (fastc) bar_fast(cnt, RANKS * ep); else bar_slow(cnt, RANKS * ep);
    if (rank == 0 && tid < CROWS) {
        float s = 0.f;
        #pragma unroll
        for (int rk = 0; rk < RANKS; ++rk) s += osum[(size_t)(r0 + tid) * RANKS + rk];
        out[r0 + tid] = sigmoid_f(s + bo[0]);
    }
}

extern "C" void kernel_launch(void* const* d_in, const int* in_sizes, int n_in,
                              void* d_out, int out_size, void* d_ws, size_t ws_size,
                              hipStream_t stream) {
    const float* x    = (const float*)d_in[0];
    const float* xl   = (const float*)d_in[1];
    const float* itv  = (const float*)d_in[2];
    const float* msk  = (const float*)d_in[3];
    const float* Wgx  = (const float*)d_in[4];
    const float* bgx  = (const float*)d_in[5];
    const float* Wgh  = (const float*)d_in[6];
    const float* bgh  = (const float*)d_in[7];
    const float* Wz   = (const float*)d_in[8];
    const float* bz   = (const float*)d_in[9];
    const float* Wr   = (const float*)d_in[10];
    const float* br   = (const float*)d_in[11];
    const float* Wh   = (const float*)d_in[12];
    const float* bh   = (const float*)d_in[13];
    const float* Wo   = (const float*)d_in[14];
    const float* bo   = (const float*)d_in[15];

    char* ws = (char*)d_ws;
    float*        xmean = (float*)ws;                          // 16384 B
    unsigned int* barc  = (unsigned int*)(ws + 16384);         // 16*256 B (counter + xcd slots)
    float*        osum  = (float*)(ws + 16384 + 4096);         // 262144 B
    ushort*       hdx   = (ushort*)(ws + 16384 + 4096 + 262144);            // 4 MB
    ushort*       rhx   = (ushort*)(ws + 16384 + 4096 + 262144 + 4194304);  // 4 MB

    k_init<<<1, 1024, 0, stream>>>(barc);
    k_xmean<<<B_TOT, 64, 0, stream>>>(x, msk, xmean);
    k_grud<<<CLUSTERS * RANKS, NTHR, 0, stream>>>(
        x, xl, itv, msk, Wgx, bgx, Wgh, bgh,
        Wz, bz, Wr, br, Wh, bh, Wo, bo,
        xmean, hdx, rhx, osum, barc, (float*)d_out);
}

// Round 11
// 6988.695 us; speedup vs baseline: 1.6191x; 1.0014x over previous
//
#include <hip/hip_runtime.h>
#include <stdint.h>

#define T_LEN 512
#define H_DIM 512
#define B_TOT 4096
#define GATE_D 514
#define CLUSTERS 16
#define RANKS 16        // blocks per cluster
#define CROWS 256       // batch rows per cluster
#define OWNC 32         // h-columns owned per block
#define NTHR 512        // 8 waves
#define BARPAD 256      // uints per cluster barrier slot (1KB)

typedef short s16x8 __attribute__((ext_vector_type(8)));
typedef float f32x4 __attribute__((ext_vector_type(4)));

__device__ __forceinline__ ushort f2bf(float f) {
    uint32_t u = __builtin_bit_cast(uint32_t, f);
    u += 0x7FFF + ((u >> 16) & 1);     // RNE
    return (ushort)(u >> 16);
}
__device__ __forceinline__ float sigmoid_f(float x) {
    return 1.0f / (1.0f + __expf(-x));
}
__device__ __forceinline__ float tanh_f(float x) {
    float ax = fabsf(x);
    float e  = __expf(2.0f * ax);
    float t  = 1.0f - 2.0f / (e + 1.0f);
    return copysignf(t, x);
}
__device__ __forceinline__ void vm0() {
    asm volatile("s_waitcnt vmcnt(0)" ::: "memory");
}

// ---------------- K0: masked mean over time ----------------
__global__ void k_xmean(const float* __restrict__ x, const float* __restrict__ m,
                        float* __restrict__ xmean) {
    int b = blockIdx.x;
    int l = threadIdx.x;
    const float* xr = x + (size_t)b * T_LEN;
    const float* mr = m + (size_t)b * T_LEN;
    float sx = 0.f, sm = 0.f;
    #pragma unroll
    for (int i = 0; i < T_LEN / 64; ++i) {
        float mv = mr[l + i * 64];
        sx += xr[l + i * 64] * mv;
        sm += mv;
    }
    for (int off = 32; off; off >>= 1) {
        sx += __shfl_down(sx, off);
        sm += __shfl_down(sm, off);
    }
    if (l == 0) xmean[b] = sx / sm;
}

// ---------------- K_init: zero cluster barrier slots ----------------
__global__ void k_init(unsigned int* barc) {
    int i = threadIdx.x + blockIdx.x * blockDim.x;
    if (i < CLUSTERS * BARPAD) barc[i] = 0u;
}

// ---------------- fenced block-wide cluster barrier (round-4/8 proven; pre/post loop) ----------------
__device__ __forceinline__ void bar_slow(unsigned int* cnt, unsigned int target) {
    vm0();
    __syncthreads();
    if (threadIdx.x == 0) {
        __builtin_amdgcn_fence(__ATOMIC_RELEASE, "agent");
        __hip_atomic_fetch_add(cnt, 1u, __ATOMIC_RELAXED, __HIP_MEMORY_SCOPE_AGENT);
        while (__hip_atomic_load(cnt, __ATOMIC_RELAXED, __HIP_MEMORY_SCOPE_AGENT) < target)
            __builtin_amdgcn_s_sleep(1);
        __builtin_amdgcn_fence(__ATOMIC_ACQUIRE, "agent");
    }
    __syncthreads();
}

// ---------------- per-wave-index cluster events ----------------
// Wave wv of each rank depends ONLY on wave wv of all 16 ranks (fragment row-tiles
// are wave-partitioned). arrive: drain own stores (write-through L1 -> L2-visible),
// one relaxed agent atomic per wave. wait: all-lane relaxed poll (single broadcast
// load), then per-wave L1 flash-invalidate (fast path) or acquire fence (fallback).
__device__ __forceinline__ void wave_arrive(unsigned int* cw, bool fastc) {
    vm0();
    if ((threadIdx.x & 63) == 0) {
        if (!fastc) __builtin_amdgcn_fence(__ATOMIC_RELEASE, "agent");
        __hip_atomic_fetch_add(cw, 1u, __ATOMIC_RELAXED, __HIP_MEMORY_SCOPE_AGENT);
    }
}
__device__ __forceinline__ void wave_wait(unsigned int* cw, unsigned int target, bool fastc) {
    while (__hip_atomic_load(cw, __ATOMIC_RELAXED, __HIP_MEMORY_SCOPE_AGENT) < target)
        __builtin_amdgcn_s_sleep(1);
    if (fastc) { asm volatile("buffer_inv" ::: "memory"); vm0(); }
    else __builtin_amdgcn_fence(__ATOMIC_ACQUIRE, "agent");
}

// ---------------- main persistent kernel ----------------
// 256 blocks x 512 threads, 1 block/CU. Cluster = 16 blocks sharing 256 batch rows
// (same-XCD by b%8 heuristic, runtime-verified via HW_REG_XCC_ID; fenced fallback).
// Block rank j owns 32 output cols; fp32 h-state in 16 regs/thread. NO block-wide
// sync in the time loop: 8 independent per-wave-index pipelines, each synced across
// ranks by 2 events/step. Events: e=2t+1 hd(t) ready; e=2t+2 rhd(t) ready.
__global__ __launch_bounds__(NTHR) void k_grud(
    const float* __restrict__ x,   const float* __restrict__ xl,
    const float* __restrict__ itv, const float* __restrict__ msk,
    const float* __restrict__ Wgx, const float* __restrict__ bgx,
    const float* __restrict__ Wgh, const float* __restrict__ bgh,
    const float* __restrict__ Wz,  const float* __restrict__ bz,
    const float* __restrict__ Wr,  const float* __restrict__ br,
    const float* __restrict__ Wh,  const float* __restrict__ bh,
    const float* __restrict__ Wo,  const float* __restrict__ bo,
    const float* __restrict__ xmean,
    ushort* __restrict__ hdx, ushort* __restrict__ rhx,
    float* __restrict__ osum, unsigned int* __restrict__ barc,
    float* __restrict__ out)
{
    __shared__ ushort wfrag[96 * 512];        // 98304 B  B-frags: z 0-31, r 32-63, h 64-95
    __shared__ ushort stage[16 * 512];        // 16384 B  frag image; wave wv owns frags 2wv,2wv+1
    __shared__ float  xi_w[8][32], mts_w[8][32], itn_w[8][32];  // 3072 B wave-private scalars
    __shared__ float4 epi_s[96];              // 1536 B   {bias, W[:,0], W[:,513]} per gate/own col
    __shared__ float2 ghb_s[OWNC];            // 256 B    {Wgh, bgh} own cols
    __shared__ unsigned int flag_s;

    const int tid = threadIdx.x;
    const int b   = blockIdx.x;
    const int cluster = (b & 7) * 2 + ((b >> 3) >> 4);   // same-XCD grouping heuristic
    const int rank    = (b >> 3) & 15;
    const int wv = tid >> 6, l = tid & 63;
    const int colb = l & 15, qg = l >> 4;
    const int r0 = cluster * CROWS;

    unsigned int* base    = barc + cluster * BARPAD;   // [0] slow cnt, [4..19] xcd, [64+16w] wave cnt
    unsigned int* xcd_arr = base + 4;
    unsigned int* cw      = base + 64 + wv * 16;       // per-wave-index counter (64B apart)
    ushort* hdc = hdx + (size_t)cluster * CROWS * H_DIM;
    ushort* rhc = rhx + (size_t)cluster * CROWS * H_DIM;
    const s16x8* WF = (const s16x8*)wfrag;
    const s16x8* HD = (const s16x8*)hdc;
    const s16x8* RH = (const s16x8*)rhc;

    // ---- one-time init: weight fragments (LDS) ----
    for (int s = tid; s < 96 * 64; s += NTHR) {
        int fi = s >> 6, ln = s & 63;
        int g = fi >> 5, nt = (fi >> 4) & 1, kt = fi & 15;
        const float* W = (g == 0) ? Wz : (g == 1) ? Wr : Wh;
        int colg = rank * OWNC + nt * 16 + (ln & 15);
        int c0 = 1 + kt * 32 + (ln >> 4) * 8;
        ushort tb[8];
        #pragma unroll
        for (int j = 0; j < 8; ++j) tb[j] = f2bf(W[(size_t)colg * GATE_D + c0 + j]);
        *(s16x8*)&wfrag[s * 8] = *(s16x8*)tb;
    }
    for (int i = tid; i < 96; i += NTHR) {
        int g = i >> 5, c = i & 31;
        const float* W  = (g == 0) ? Wz : (g == 1) ? Wr : Wh;
        const float* bb = (g == 0) ? bz : (g == 1) ? br : bh;
        int colg = rank * OWNC + c;
        epi_s[i] = make_float4(bb[colg], W[(size_t)colg * GATE_D],
                               W[(size_t)colg * GATE_D + GATE_D - 1], 0.f);
    }
    if (tid < OWNC) ghb_s[tid] = make_float2(Wgh[rank * OWNC + tid], bgh[rank * OWNC + tid]);
    const float wgx = Wgx[0], bgx0 = bgx[0];
    const float xmv = (l < 32) ? xmean[r0 + wv * 32 + l] : 0.f;

    // ---- registration: publish XCC_ID, fenced barrier, verify cluster uniformity ----
    if (tid == 0) {
        unsigned int myxcc;
        asm volatile("s_getreg_b32 %0, hwreg(HW_REG_XCC_ID)" : "=s"(myxcc));
        xcd_arr[rank] = myxcc;
    }
    bar_slow(base, RANKS);                     // slow-counter use #1
    if (tid == 0) {
        unsigned int x0 = xcd_arr[0], same = 1;
        #pragma unroll
        for (int rk = 1; rk < RANKS; ++rk) same &= (xcd_arr[rk] == x0) ? 1u : 0u;
        flag_s = same;
    }
    __syncthreads();
    const bool fastc = (flag_s != 0);

    // ---- publish hd(0)=0 for own frags (wave-private) + event 1 ----
    #pragma unroll
    for (int i = 0; i < 2; ++i) {
        int f = 2 * wv + i;
        *(s16x8*)((char*)hdc + (((size_t)f * 16 + rank) * 64 + l) * 16) = (s16x8){0,0,0,0,0,0,0,0};
    }
    wave_arrive(cw, fastc);

    float hdq[2][2][4];                        // fp32 h-state in registers (decayed hd)
    #pragma unroll
    for (int mt = 0; mt < 2; ++mt)
        #pragma unroll
        for (int nt = 0; nt < 2; ++nt)
            #pragma unroll
            for (int q = 0; q < 4; ++q) hdq[mt][nt][q] = 0.f;
    float zq[2][2][4];

    for (int t = 0; t < T_LEN; ++t) {
        // ---- per-wave scalars for t (overlaps event poll) ----
        if (l < 32) {
            size_t idx = (size_t)(r0 + wv * 32 + l) * T_LEN + t;
            float xv = x[idx], xlv = xl[idx], iv = itv[idx], mv = msk[idx];
            float gx = __expf(-fmaxf(iv * wgx + bgx0, 0.f));
            xi_w[wv][l]  = mv * xv + (1.f - mv) * (gx * xlv + (1.f - gx) * xmv);
            mts_w[wv][l] = mv;
        }
        wave_wait(cw, (unsigned int)(16 * (2 * t + 1)), fastc);   // hd(t) ready (this wave-index)

        // ---- GEMM1: z,r for rows [32wv,32wv+32) x own 32 cols ----
        f32x4 accz[2][2], accr[2][2];
        #pragma unroll
        for (int mt = 0; mt < 2; ++mt)
            #pragma unroll
            for (int nt = 0; nt < 2; ++nt) { accz[mt][nt] = (f32x4){0,0,0,0}; accr[mt][nt] = (f32x4){0,0,0,0}; }
        #pragma unroll
        for (int kt = 0; kt < 16; ++kt) {
            s16x8 a0 = HD[((2 * wv    ) * 16 + kt) * 64 + l];
            s16x8 a1 = HD[((2 * wv + 1) * 16 + kt) * 64 + l];
            #pragma unroll
            for (int nt = 0; nt < 2; ++nt) {
                s16x8 bz_ = WF[(     nt * 16 + kt) * 64 + l];
                s16x8 br_ = WF[(32 + nt * 16 + kt) * 64 + l];
                accz[0][nt] = __builtin_amdgcn_mfma_f32_16x16x32_bf16(a0, bz_, accz[0][nt], 0, 0, 0);
                accz[1][nt] = __builtin_amdgcn_mfma_f32_16x16x32_bf16(a1, bz_, accz[1][nt], 0, 0, 0);
                accr[0][nt] = __builtin_amdgcn_mfma_f32_16x16x32_bf16(a0, br_, accr[0][nt], 0, 0, 0);
                accr[1][nt] = __builtin_amdgcn_mfma_f32_16x16x32_bf16(a1, br_, accr[1][nt], 0, 0, 0);
            }
        }
        // ---- z,r epilogue: z -> regs, r*hd -> stage (wave-own frags) ----
        #pragma unroll
        for (int mt = 0; mt < 2; ++mt) {
            #pragma unroll
            for (int nt = 0; nt < 2; ++nt) {
                int c = nt * 16 + colb;
                float4 ez = epi_s[c];
                float4 er = epi_s[32 + c];
                int grp = (c >> 3) & 3, jj = c & 7;
                #pragma unroll
                for (int q = 0; q < 4; ++q) {
                    int lr = mt * 16 + qg * 4 + q;            // local row in wave
                    float xiv = xi_w[wv][lr], mtv = mts_w[wv][lr];
                    zq[mt][nt][q] = sigmoid_f(accz[mt][nt][q] + ez.x + xiv * ez.y + mtv * ez.z);
                    float rr = sigmoid_f(accr[mt][nt][q] + er.x + xiv * er.y + mtv * er.z);
                    stage[(((2 * wv + mt) * 64) + (qg * 4 + q) + grp * 16) * 8 + jj] =
                        f2bf(rr * hdq[mt][nt][q]);
                }
            }
        }
        // ---- wave-private copy stage -> rhc ----
        #pragma unroll
        for (int i = 0; i < 2; ++i) {
            int f = 2 * wv + i;
            *(s16x8*)((char*)rhc + (((size_t)f * 16 + rank) * 64 + l) * 16) =
                *(const s16x8*)&stage[(f * 64 + l) * 8];
        }
        wave_arrive(cw, fastc);                                   // event 2t+2: rhd(t) published

        if (l < 32 && t + 1 < T_LEN)                              // its(t+1) overlaps poll
            itn_w[wv][l] = itv[(size_t)(r0 + wv * 32 + l) * T_LEN + t + 1];
        wave_wait(cw, (unsigned int)(16 * (2 * t + 2)), fastc);   // rhd(t) ready

        // ---- GEMM2: h~ ----
        f32x4 acc2[2][2];
        #pragma unroll
        for (int mt = 0; mt < 2; ++mt)
            #pragma unroll
            for (int nt = 0; nt < 2; ++nt) acc2[mt][nt] = (f32x4){0,0,0,0};
        #pragma unroll
        for (int kt = 0; kt < 16; ++kt) {
            s16x8 a0 = RH[((2 * wv    ) * 16 + kt) * 64 + l];
            s16x8 a1 = RH[((2 * wv + 1) * 16 + kt) * 64 + l];
            #pragma unroll
            for (int nt = 0; nt < 2; ++nt) {
                s16x8 bh_ = WF[(64 + nt * 16 + kt) * 64 + l];
                acc2[0][nt] = __builtin_amdgcn_mfma_f32_16x16x32_bf16(a0, bh_, acc2[0][nt], 0, 0, 0);
                acc2[1][nt] = __builtin_amdgcn_mfma_f32_16x16x32_bf16(a1, bh_, acc2[1][nt], 0, 0, 0);
            }
        }
        // ---- h~ epilogue + fused state update + fused gamma(t+1) decay ----
        const bool last = (t + 1 == T_LEN);
        #pragma unroll
        for (int mt = 0; mt < 2; ++mt) {
            #pragma unroll
            for (int nt = 0; nt < 2; ++nt) {
                int c = nt * 16 + colb;
                float4 eh = epi_s[64 + c];
                float2 gb = ghb_s[c];
                int grp = (c >> 3) & 3, jj = c & 7;
                #pragma unroll
                for (int q = 0; q < 4; ++q) {
                    int lr = mt * 16 + qg * 4 + q;
                    float ht = tanh_f(acc2[mt][nt][q] + eh.x + xi_w[wv][lr] * eh.y + mts_w[wv][lr] * eh.z);
                    float hd = hdq[mt][nt][q];
                    float hn = hd + zq[mt][nt][q] * (ht - hd);
                    float g  = last ? 1.f : __expf(-fmaxf(itn_w[wv][lr] * gb.x + gb.y, 0.f));
                    float hdn = hn * g;
                    hdq[mt][nt][q] = hdn;
                    if (!last)
                        stage[(((2 * wv + mt) * 64) + (qg * 4 + q) + grp * 16) * 8 + jj] = f2bf(hdn);
                }
            }
        }
        if (!last) {
            #pragma unroll
            for (int i = 0; i < 2; ++i) {
                int f = 2 * wv + i;
                *(s16x8*)((char*)hdc + (((size_t)f * 16 + rank) * 64 + l) * 16) =
                    *(const s16x8*)&stage[(f * 64 + l) * 8];
            }
        }
        wave_arrive(cw, fastc);                                   // event 2t+3: hd(t+1) published
    }

    // ---- output head: per-thread partials over own cols, 16-lane shfl reduce ----
    {
        float wo0 = Wo[rank * OWNC + colb];
        float wo1 = Wo[rank * OWNC + 16 + colb];
        #pragma unroll
        for (int mt = 0; mt < 2; ++mt) {
            #pragma unroll
            for (int q = 0; q < 4; ++q) {
                int row = wv * 32 + mt * 16 + qg * 4 + q;
                float p = hdq[mt][0][q] * wo0 + hdq[mt][1][q] * wo1;
                #pragma unroll
                for (int off = 1; off < 16; off <<= 1) p += __shfl_xor(p, off);
                if (colb == 0) osum[(size_t)(r0 + row) * RANKS + rank] = p;
            }
        }
    }
    bar_slow(base, 2 * RANKS);                 // slow-counter use #2 (fenced, any placement)
    if (rank == 0 && tid < CROWS) {
        float s = 0.f;
        #pragma unroll
        for (int rk = 0; rk < RANKS; ++rk) s += osum[(size_t)(r0 + tid) * RANKS + rk];
        out[r0 + tid] = sigmoid_f(s + bo[0]);
    }
}

extern "C" void kernel_launch(void* const* d_in, const int* in_sizes, int n_in,
                              void* d_out, int out_size, void* d_ws, size_t ws_size,
                              hipStream_t stream) {
    const float* x    = (const float*)d_in[0];
    const float* xl   = (const float*)d_in[1];
    const float* itv  = (const float*)d_in[2];
    const float* msk  = (const float*)d_in[3];
    const float* Wgx  = (const float*)d_in[4];
    const float* bgx  = (const float*)d_in[5];
    const float* Wgh  = (const float*)d_in[6];
    const float* bgh  = (const float*)d_in[7];
    const float* Wz   = (const float*)d_in[8];
    const float* bz   = (const float*)d_in[9];
    const float* Wr   = (const float*)d_in[10];
    const float* br   = (const float*)d_in[11];
    const float* Wh   = (const float*)d_in[12];
    const float* bh   = (const float*)d_in[13];
    const float* Wo   = (const float*)d_in[14];
    const float* bo   = (const float*)d_in[15];

    char* ws = (char*)d_ws;
    float*        xmean = (float*)ws;                               // 16384 B
    unsigned int* barc  = (unsigned int*)(ws + 16384);              // 16*1024 B = 16384 B
    float*        osum  = (float*)(ws + 32768);                     // 262144 B
    ushort*       hdx   = (ushort*)(ws + 32768 + 262144);           // 4 MB
    ushort*       rhx   = (ushort*)(ws + 32768 + 262144 + 4194304); // 4 MB

    k_init<<<16, 256, 0, stream>>>(barc);
    k_xmean<<<B_TOT, 64, 0, stream>>>(x, msk, xmean);
    k_grud<<<CLUSTERS * RANKS, NTHR, 0, stream>>>(
        x, xl, itv, msk, Wgx, bgx, Wgh, bgh,
        Wz, bz, Wr, br, Wh, bh, Wo, bo,
        xmean, hdx, rhx, osum, barc, (float*)d_out);
}